// Round 1
// 121.095 us; speedup vs baseline: 1.0436x; 1.0436x over previous
//
#include <hip/hip_runtime.h>

// Speech MSA with dynamic windows.
// B=4, T=4160 (W=64 word tokens + F=4096 frames), E=256, H=4, D=64,
// LOCAL_SIZE=15 (pad 7), chunk = F/W = 64, n = B*H = 16.
//
// R13: R12 structure (126.4 us) +
//  - x pre-converted to f16 (xh) once in conv_small; qkv_mfma/out_mfma A-path
//    reads f16 directly (halves A traffic: 100MB->50MB across the 6 N-blocks,
//    removes 16 v_cvt per thread per K-step from the qkv main loop).
//    Bit-identical numerics: same (_Float16)x rounding, done once.
//  - attn staging via h8 (16B) global loads instead of h4 (8B).
//  - expf -> __expf in attn softmax (native v_exp path, ~1e-5 rel err).

#define QN 4194304ull  // 16 * 4096 * 64 elements (head-layout buffers)

typedef _Float16 h8 __attribute__((ext_vector_type(8)));
typedef _Float16 h4 __attribute__((ext_vector_type(4)));
typedef float f32x16 __attribute__((ext_vector_type(16)));

// ------------------------------------------------- small conversion kernel
// g [0,768):     WqT [768][256] f16
// g [768,1024):  WoT [256][256] f16
// g [1024,1280): wmT [b][f][w]  f16 (LDS 64x64 tile transpose)
// g [1280,1284): xT  [b][c][w]  f16 (word-token rows transposed)
// g [1284,2324): xh  [b][t][e]  f16 (full x, same layout)
__global__ __launch_bounds__(256) void conv_small(
    const float* __restrict__ x, const float* __restrict__ wm,
    const float* __restrict__ Wq, const float* __restrict__ Wo,
    _Float16* __restrict__ wqth, _Float16* __restrict__ woth,
    _Float16* __restrict__ wmth, _Float16* __restrict__ xth,
    _Float16* __restrict__ xh) {
  __shared__ float S[64 * 65];
  const int g = blockIdx.x, tid = threadIdx.x;
  if (g < 768) {
    int o = g * 256 + tid;
    int n = o >> 8, k = o & 255;
    wqth[o] = (_Float16)Wq[(size_t)k * 768 + n];
  } else if (g < 1024) {
    int o = (g - 768) * 256 + tid;
    int n = o >> 8, k = o & 255;
    woth[o] = (_Float16)Wo[(size_t)k * 256 + n];
  } else if (g < 1280) {
    int local = g - 1024;
    int b = local >> 6, f0 = (local & 63) * 64;
    {
      int w = tid >> 2, c0 = (tid & 3) * 16;
      const float* src = wm + ((size_t)(b * 64 + w)) * 4096 + f0 + c0;
#pragma unroll
      for (int cc = 0; cc < 16; cc += 4)
        *(float4*)&S[w * 65 + c0 + cc] = *(const float4*)(src + cc);
    }
    __syncthreads();
    {
      int fl = tid >> 2, w0 = (tid & 3) * 16;
      int f = f0 + fl;
      _Float16 hh[16];
#pragma unroll
      for (int j = 0; j < 16; ++j) hh[j] = (_Float16)S[(w0 + j) * 65 + fl];
      size_t o = ((size_t)b * 4096 + f) * 64 + w0;
      *(float4*)(wmth + o) = *(float4*)&hh[0];
      *(float4*)(wmth + o + 8) = *(float4*)&hh[8];
    }
  } else if (g < 1284) {
    int b = g - 1280;
    for (int c0 = 0; c0 < 256; c0 += 64) {
      __syncthreads();
      {
        int w = tid >> 2, cl0 = (tid & 3) * 16;
        const float* src = x + ((size_t)(b * 4160 + w)) * 256 + c0 + cl0;
#pragma unroll
        for (int cc = 0; cc < 16; cc += 4)
          *(float4*)&S[w * 65 + cl0 + cc] = *(const float4*)(src + cc);
      }
      __syncthreads();
      {
        int cl = tid >> 2, w0 = (tid & 3) * 16;
        _Float16 hh[16];
#pragma unroll
        for (int j = 0; j < 16; ++j) hh[j] = (_Float16)S[(w0 + j) * 65 + cl];
        size_t o = ((size_t)(b * 256 + c0 + cl)) * 64 + w0;
        *(float4*)(xth + o) = *(float4*)&hh[0];
        *(float4*)(xth + o + 8) = *(float4*)&hh[8];
      }
    }
  } else {
    // full x -> f16, identical layout. 1040 blocks x 4096 elements.
    size_t base = (size_t)(g - 1284) * 4096 + (size_t)tid * 4;
#pragma unroll
    for (int c = 0; c < 4; ++c) {
      float4 v = *(const float4*)(x + base + c * 1024);
      h4 hv = {(_Float16)v.x, (_Float16)v.y, (_Float16)v.z, (_Float16)v.w};
      *(h4*)(xh + base + c * 1024) = hv;
    }
  }
}

// ---------------------------------------------------------------- K1: QKV gemm
// M=16384, N=768, K=256. Block 128x128, 4 waves (each 64x64), BK=32 x 8 iters.
// A read as pre-converted f16 (no in-loop cvt). Epilogue writes f16 Q/K/V.
__global__ __launch_bounds__(256) void qkv_mfma(
    const _Float16* __restrict__ xh, const _Float16* __restrict__ wth,
    const float* __restrict__ bq,
    _Float16* __restrict__ Qh, _Float16* __restrict__ Kh,
    _Float16* __restrict__ Vh) {
  __shared__ _Float16 Ah[128][40], Bh[128][40];
  const int tid = threadIdx.x;
  const int wave = tid >> 6, lane = tid & 63;
  const int ln = lane & 31, half = lane >> 5;
  const int mw = (wave & 1) * 64, nw = (wave >> 1) * 64;
  const int m0 = blockIdx.x * 128, n0 = blockIdx.y * 128;

  const int sr = tid >> 1, scq = (tid & 1) * 16;
  const int am = m0 + sr;
  const size_t arow =
      ((size_t)((am >> 12) * 4160 + 64 + (am & 4095))) * 256 + scq;
  const size_t brow = (size_t)(n0 + sr) * 256 + scq;

  float4 rah0, rah1, rbh0, rbh1;
  auto QLOAD = [&](int k0_) {
    rah0 = *(const float4*)(xh + arow + k0_);
    rah1 = *(const float4*)(xh + arow + k0_ + 8);
    rbh0 = *(const float4*)(wth + brow + k0_);
    rbh1 = *(const float4*)(wth + brow + k0_ + 8);
  };

  QLOAD(0);
  f32x16 acc[2][2] = {};

  for (int it = 0; it < 8; ++it) {
    __syncthreads();
    *(float4*)&Ah[sr][scq] = rah0;
    *(float4*)&Ah[sr][scq + 8] = rah1;
    *(float4*)&Bh[sr][scq] = rbh0;
    *(float4*)&Bh[sr][scq + 8] = rbh1;
    __syncthreads();
    if (it < 7) QLOAD((it + 1) * 32);
#pragma unroll
    for (int ks = 0; ks < 2; ++ks) {
      const int kc = ks * 16 + half * 8;
      h8 a0 = *(const h8*)&Ah[mw + ln][kc];
      h8 a1 = *(const h8*)&Ah[mw + 32 + ln][kc];
      h8 b0 = *(const h8*)&Bh[nw + ln][kc];
      h8 b1 = *(const h8*)&Bh[nw + 32 + ln][kc];
      acc[0][0] = __builtin_amdgcn_mfma_f32_32x32x16_f16(a0, b0, acc[0][0], 0, 0, 0);
      acc[0][1] = __builtin_amdgcn_mfma_f32_32x32x16_f16(a0, b1, acc[0][1], 0, 0, 0);
      acc[1][0] = __builtin_amdgcn_mfma_f32_32x32x16_f16(a1, b0, acc[1][0], 0, 0, 0);
      acc[1][1] = __builtin_amdgcn_mfma_f32_32x32x16_f16(a1, b1, acc[1][1], 0, 0, 0);
    }
  }

  // C/D: col = ln, row = (reg&3) + 8*(reg>>2) + 4*half
#pragma unroll
  for (int ni = 0; ni < 2; ++ni) {
    const int c = n0 + nw + ni * 32 + ln;
    const int which = c >> 8, e = c & 255;
    const int h = e >> 6, d = e & 63;
    _Float16* dst = (which == 0) ? Qh : (which == 1) ? Kh : Vh;
    const float sc2 = (which == 0) ? 0.125f : 1.0f;
    const float bias = bq[c];
#pragma unroll
    for (int mi = 0; mi < 2; ++mi) {
      const int rb = m0 + mw + mi * 32 + 4 * half;
#pragma unroll
      for (int reg = 0; reg < 16; ++reg) {
        int rr = rb + (reg & 3) + 8 * (reg >> 2);
        int b2 = rr >> 12, f2 = rr & 4095;
        dst[(((size_t)(b2 * 4 + h)) * 4096 + f2) * 64 + d] =
            (_Float16)((acc[mi][ni][reg] + bias) * sc2);
      }
    }
  }
}

// ------------------------------------------------- K2: fused expa + attention
// Q/K/V read as f16, converted to fp32 at staging; all math fp32 as before.
__global__ __launch_bounds__(256) void attn_fused(
    const _Float16* __restrict__ Qh, const _Float16* __restrict__ Kh,
    const _Float16* __restrict__ Vh,
    const _Float16* __restrict__ wmth, const _Float16* __restrict__ xth,
    _Float16* __restrict__ OFh) {
  __shared__ float Ks[78][68];
  __shared__ float Vs[78][68];
  __shared__ float EXs[64][68];
  __shared__ float s0s[64];
  __shared__ float red[2];
  const int tid = threadIdx.x;
  const int w = blockIdx.x;
  const int n = blockIdx.y;
  const int f0 = w * 64;
  const int b = n >> 2, h = n & 3;

  for (int idx = tid; idx < 78 * 8; idx += 256) {
    int rr = idx >> 3, c = (idx & 7) * 8;
    int g = f0 - 7 + rr;
    float4 k0v = {0.f, 0.f, 0.f, 0.f}, k1v = k0v, v0v = k0v, v1v = k0v;
    if (g >= 0 && g < 4096) {
      size_t base = ((size_t)n * 4096 + g) * 64 + c;
      h8 k8 = *(const h8*)(Kh + base);
      h8 v8 = *(const h8*)(Vh + base);
      k0v = {(float)k8.s0, (float)k8.s1, (float)k8.s2, (float)k8.s3};
      k1v = {(float)k8.s4, (float)k8.s5, (float)k8.s6, (float)k8.s7};
      v0v = {(float)v8.s0, (float)v8.s1, (float)v8.s2, (float)v8.s3};
      v1v = {(float)v8.s4, (float)v8.s5, (float)v8.s6, (float)v8.s7};
    }
    *(float4*)&Ks[rr][c] = k0v;
    *(float4*)&Ks[rr][c + 4] = k1v;
    *(float4*)&Vs[rr][c] = v0v;
    *(float4*)&Vs[rr][c + 4] = v1v;
  }
  {
    const int wave = tid >> 6, lane = tid & 63;
    const int ln = lane & 31, half = lane >> 5;
    const int mi = wave & 1, ni = wave >> 1;
    const size_t arow = ((size_t)(b * 4096 + f0 + mi * 32 + ln)) * 64 + half * 8;
    const size_t brow =
        ((size_t)(b * 256 + h * 64 + ni * 32 + ln)) * 64 + half * 8;
    f32x16 eacc = {};
#pragma unroll
    for (int ks = 0; ks < 4; ++ks) {
      const int kc = ks * 16;
      h8 ah = *(const h8*)(wmth + arow + kc);
      h8 bh = *(const h8*)(xth + brow + kc);
      eacc = __builtin_amdgcn_mfma_f32_32x32x16_f16(ah, bh, eacc, 0, 0, 0);
    }
    const int col = ni * 32 + ln;
    const int rb2 = mi * 32 + 4 * half;
#pragma unroll
    for (int reg = 0; reg < 16; ++reg)
      EXs[rb2 + (reg & 3) + 8 * (reg >> 2)][col] = eacc[reg];
  }
  __syncthreads();

  const int i = tid >> 2, q = tid & 3;
  const int f = f0 + i;
  const size_t qbase = ((size_t)n * 4096 + f) * 64 + q * 16;
  h8 qh0 = *(const h8*)(Qh + qbase);
  h8 qh1 = *(const h8*)(Qh + qbase + 8);
  float4 q0 = {(float)qh0.s0, (float)qh0.s1, (float)qh0.s2, (float)qh0.s3};
  float4 q1 = {(float)qh0.s4, (float)qh0.s5, (float)qh0.s6, (float)qh0.s7};
  float4 q2 = {(float)qh1.s0, (float)qh1.s1, (float)qh1.s2, (float)qh1.s3};
  float4 q3 = {(float)qh1.s4, (float)qh1.s5, (float)qh1.s6, (float)qh1.s7};
  float4 e0 = *(const float4*)&EXs[i][q * 16];
  float4 e1 = *(const float4*)&EXs[i][q * 16 + 4];
  float4 e2 = *(const float4*)&EXs[i][q * 16 + 8];
  float4 e3 = *(const float4*)&EXs[i][q * 16 + 12];

  float s0 = q0.x * e0.x + q0.y * e0.y + q0.z * e0.z + q0.w * e0.w +
             q1.x * e1.x + q1.y * e1.y + q1.z * e1.z + q1.w * e1.w +
             q2.x * e2.x + q2.y * e2.y + q2.z * e2.z + q2.w * e2.w +
             q3.x * e3.x + q3.y * e3.y + q3.z * e3.z + q3.w * e3.w;
  s0 += __shfl_xor(s0, 1);
  s0 += __shfl_xor(s0, 2);

  float sj[15];
#pragma unroll
  for (int j = 0; j < 15; ++j) {
    const float* kr = &Ks[i + j][q * 16];
    float4 k0 = *(const float4*)(kr);
    float4 k1 = *(const float4*)(kr + 4);
    float4 k2 = *(const float4*)(kr + 8);
    float4 k3 = *(const float4*)(kr + 12);
    float s = q0.x * k0.x + q0.y * k0.y + q0.z * k0.z + q0.w * k0.w +
              q1.x * k1.x + q1.y * k1.y + q1.z * k1.z + q1.w * k1.w +
              q2.x * k2.x + q2.y * k2.y + q2.z * k2.z + q2.w * k2.w +
              q3.x * k3.x + q3.y * k3.y + q3.z * k3.z + q3.w * k3.w;
    s += __shfl_xor(s, 1);
    s += __shfl_xor(s, 2);
    sj[j] = s;
  }

  if (q == 0) s0s[i] = s0;
  __syncthreads();
  if (tid < 64) {
    float v = s0s[tid];
    float m = v;
    for (int o = 1; o < 64; o <<= 1) m = fmaxf(m, __shfl_xor(m, o));
    float ee = __expf(v - m);
    float s = ee;
    for (int o = 1; o < 64; o <<= 1) s += __shfl_xor(s, o);
    if (tid == 0) { red[0] = m; red[1] = s; }
  }
  __syncthreads();
  const float wt = __expf(s0 - red[0]) / red[1];

  float mx = sj[0];
#pragma unroll
  for (int j = 1; j < 15; ++j) mx = fmaxf(mx, sj[j]);
  float pj[15], den = 0.f;
#pragma unroll
  for (int j = 0; j < 15; ++j) { pj[j] = __expf(sj[j] - mx); den += pj[j]; }
  const float inv = 1.0f / den;

  float o[16] = {wt * e0.x, wt * e0.y, wt * e0.z, wt * e0.w,
                 wt * e1.x, wt * e1.y, wt * e1.z, wt * e1.w,
                 wt * e2.x, wt * e2.y, wt * e2.z, wt * e2.w,
                 wt * e3.x, wt * e3.y, wt * e3.z, wt * e3.w};
#pragma unroll
  for (int j = 0; j < 15; ++j) {
    float wj = pj[j] * inv;
    const float* vr = &Vs[i + j][q * 16];
#pragma unroll
    for (int dd = 0; dd < 16; ++dd) o[dd] = fmaf(wj, vr[dd], o[dd]);
  }
  _Float16 oh[16];
#pragma unroll
  for (int dd = 0; dd < 16; ++dd) oh[dd] = (_Float16)o[dd];
  *(float4*)(OFh + qbase) = *(float4*)&oh[0];
  *(float4*)(OFh + qbase + 8) = *(float4*)&oh[8];
}

// ---------------------------------------------------------------- K3: out proj
// M=16640, N=256, K=256. Block 64x64, 4 waves (each 32x32), BK=64 x 4 iters.
// A read as f16 (xh for word-token rows, OFh for frame rows).
__global__ __launch_bounds__(256) void out_mfma(
    const _Float16* __restrict__ xh, const _Float16* __restrict__ ofh,
    const _Float16* __restrict__ wth, const float* __restrict__ bo,
    float* __restrict__ out) {
  __shared__ _Float16 Ah[64][72], Bh[64][72];
  const int tid = threadIdx.x;
  const int wave = tid >> 6, lane = tid & 63;
  const int ln = lane & 31, half = lane >> 5;
  const int mw = (wave & 1) * 32, nw = (wave >> 1) * 32;
  const int m0 = blockIdx.x * 64, n0 = blockIdx.y * 64;
  const int sr = tid >> 2, sc4 = (tid & 3) * 16;
  const int m = m0 + sr;
  const int b = m / 4160, tt = m % 4160;
  const bool useX = (tt < 64);
  const size_t xrow = ((size_t)(b * 4160 + tt)) * 256 + sc4;  // f16 xh
  const long obase = ((long)(b * 4) * 4096 + (tt - 64)) * 64 + sc4;
  const size_t bbase = (size_t)(n0 + sr) * 256 + sc4;

  float4 ra0, ra1, rb0, rb1;
  auto OLOAD = [&](int k0_) {
    if (useX) {
      ra0 = *(const float4*)(xh + xrow + k0_);
      ra1 = *(const float4*)(xh + xrow + k0_ + 8);
    } else {
      size_t o_ = (size_t)(obase + (long)(k0_ >> 6) * 262144);
      ra0 = *(const float4*)(ofh + o_);
      ra1 = *(const float4*)(ofh + o_ + 8);
    }
    rb0 = *(const float4*)(wth + bbase + k0_);
    rb1 = *(const float4*)(wth + bbase + k0_ + 8);
  };

  OLOAD(0);
  f32x16 acc = {};
  for (int it = 0; it < 4; ++it) {
    __syncthreads();
    *(float4*)&Ah[sr][sc4] = ra0;
    *(float4*)&Ah[sr][sc4 + 8] = ra1;
    *(float4*)&Bh[sr][sc4] = rb0;
    *(float4*)&Bh[sr][sc4 + 8] = rb1;
    __syncthreads();
    if (it < 3) OLOAD((it + 1) * 64);
#pragma unroll
    for (int ks = 0; ks < 4; ++ks) {
      const int kc = ks * 16 + half * 8;
      h8 ah = *(const h8*)&Ah[mw + ln][kc];
      h8 bh = *(const h8*)&Bh[nw + ln][kc];
      acc = __builtin_amdgcn_mfma_f32_32x32x16_f16(ah, bh, acc, 0, 0, 0);
    }
  }
  const int c = n0 + nw + ln;
  const float bias = bo[c];
  const int rb = m0 + mw + 4 * half;
#pragma unroll
  for (int reg = 0; reg < 16; ++reg) {
    int rr = rb + (reg & 3) + 8 * (reg >> 2);
    out[(size_t)rr * 256 + c] = acc[reg] + bias;
  }
}

// ---------------------------------------------------------------- launch
extern "C" void kernel_launch(void* const* d_in, const int* in_sizes, int n_in,
                              void* d_out, int out_size, void* d_ws, size_t ws_size,
                              hipStream_t stream) {
  const float* x  = (const float*)d_in[0];
  const float* wm = (const float*)d_in[1];
  const float* Wq = (const float*)d_in[2];
  const float* bq = (const float*)d_in[3];
  const float* Wo = (const float*)d_in[4];
  const float* bo = (const float*)d_in[5];
  float* out = (float*)d_out;

  _Float16* Qh   = (_Float16*)d_ws;  // f16 head-layout, QN each
  _Float16* Kh   = Qh + QN;
  _Float16* Vh   = Kh + QN;
  _Float16* OFh  = Vh + QN;
  _Float16* Wqth = OFh + QN;        // [768][256]
  _Float16* Woth = Wqth + 196608;   // [256][256]
  _Float16* wmTh = Woth + 65536;    // [4][4096][64]
  _Float16* xTh  = wmTh + 1048576;  // [4][256][64]
  _Float16* xh   = xTh + 65536;     // [4][4160][256] full x in f16
  // total ~45 MB of workspace

  conv_small<<<dim3(2324), 256, 0, stream>>>(x, wm, Wq, Wo, Wqth, Woth, wmTh,
                                             xTh, xh);
  qkv_mfma<<<dim3(128, 6), 256, 0, stream>>>(xh, Wqth, bq, Qh, Kh, Vh);
  attn_fused<<<dim3(64, 16), 256, 0, stream>>>(Qh, Kh, Vh, wmTh, xTh, OFh);
  out_mfma<<<dim3(260, 4), 256, 0, stream>>>(xh, OFh, Woth, bo, out);
}